// Round 5
// baseline (22699.928 us; speedup 1.0000x reference)
//
#include <hip/hip_runtime.h>
#include <float.h>

#define V 50000
#define E 100
#define H 512
#define T 200
#define B 256
#define NC 5
#define HB (H * B)
#define NBLK 256

// ---------------- activations (fast, ~2e-7 abs err) ----------------
__device__ __forceinline__ float fsig(float x)  { return 1.f / (1.f + __expf(-x)); }
__device__ __forceinline__ float ftanh(float x) { return 1.f - 2.f / (__expf(2.f * x) + 1.f); }

// ws layout (floats): h0[2][H][B] | c0[H][B] | h1[2][H][B] | c1[H][B] | hmax[H][B]
//                     | last[B](int) | cnt(unsigned)
__global__ void k_init(float* __restrict__ ws, const int* __restrict__ X,
                       int* __restrict__ last, unsigned* __restrict__ cnt) {
    int i = blockIdx.x * 256 + threadIdx.x;
    if (i < 6 * HB)       ws[i] = 0.f;
    else if (i < 7 * HB)  ws[i] = -FLT_MAX;
    if (i < B) {
        int l = -1;
        const int* xr = X + i * T;
        for (int t = 0; t < T; ++t)
            if (xr[t] != V) l = t;
        last[i] = l;
    }
    if (i < 32) cnt[i] = 0u;
}

// ---------------- one layer-phase of one step (per block) ----------------
// Block tile: 32 b x 16 j x 4 gates. K split across the two 128-thread halves.
// L0 half0: emb K=100(pad128, 4 chunks) + rec k 0..191 (6 chunks)  [10 chunks]
// L0 half1: rec k 192..511                                          [10 chunks]
// L1 half0: x = h0[tt], k 0..511; half1: rec h1[tt-1], k 0..511     [16 chunks]
// LDS per half: xb 2x[32k][32b], wb 2x[32k][64c]; double-buffered, 1 sync/chunk.
template <bool L0>
__device__ __forceinline__ void run_phase(
    int t,                                     // L0: t ; L1: tt
    const int* __restrict__ X, const float* __restrict__ embp,
    const float* __restrict__ xsrc,            // half0 source ([k][B])
    const float* __restrict__ hsrc,            // half1 source ([k][B])
    const float* __restrict__ Wx, const float* __restrict__ Wh,
    const float* __restrict__ bias, float* __restrict__ cst,
    float* __restrict__ hout, float* __restrict__ hmaxp,
    const int* __restrict__ last,
    const int half, const int tid2, const int b0g, const int jt, const int wrow,
    float* __restrict__ xb, float* __restrict__ wb, float* __restrict__ redS)
{
    const int NCH = L0 ? 10 : 16;
    const int s_kl = tid2 >> 3;            // rec-x: k row 0..15
    const int s_b4 = (tid2 & 7) * 4;       //        b col
    const int s_bl = tid2 & 31;            // emb-x: b row
    const int s_kg = tid2 >> 5;            //        k group 0..3
    const int s_cl = tid2 & 63;            // w: column c = jl*4+g
    const int s_kh = tid2 >> 6;            //    k half 0/1
    const int bthr = tid2 >> 4;            // fma: b slot 0..7
    const int jthr = tid2 & 15;            //      j slot 0..15

    float acc[4][4] = {{0,0,0,0},{0,0,0,0},{0,0,0,0},{0,0,0,0}};
    float4 rx0, rx1, rw[4];

    auto loadc = [&](int ch) {
        if (half == 0) {
            if (L0 && ch < 4) {
                const int kb = ch * 32;
                const int row = X[(b0g + s_bl) * T + t];
                const float* er = embp + (size_t)row * E;
                const int k0 = kb + s_kg * 4, k1 = k0 + 16;
                rx0 = (k0 < E) ? *(const float4*)(er + k0) : make_float4(0,0,0,0);
                rx1 = (k1 < E) ? *(const float4*)(er + k1) : make_float4(0,0,0,0);
                const float* wr = Wx + (size_t)wrow * E;
#pragma unroll
                for (int q = 0; q < 4; ++q) {
                    int k = kb + s_kh * 16 + q * 4;
                    rw[q] = (k < E) ? *(const float4*)(wr + k) : make_float4(0,0,0,0);
                }
            } else {
                const int kb = L0 ? (ch - 4) * 32 : ch * 32;
                const float* p = xsrc + (size_t)(kb + s_kl) * B + b0g + s_b4;
                rx0 = *(const float4*)p;
                rx1 = *(const float4*)(p + 16 * B);
                const float* wr = (L0 ? Wh : Wx) + (size_t)wrow * H + kb;
#pragma unroll
                for (int q = 0; q < 4; ++q)
                    rw[q] = *(const float4*)(wr + s_kh * 16 + q * 4);
            }
        } else {
            const int kb = (L0 ? 192 : 0) + ch * 32;
            const float* p = hsrc + (size_t)(kb + s_kl) * B + b0g + s_b4;
            rx0 = *(const float4*)p;
            rx1 = *(const float4*)(p + 16 * B);
            const float* wr = Wh + (size_t)wrow * H + kb;
#pragma unroll
            for (int q = 0; q < 4; ++q)
                rw[q] = *(const float4*)(wr + s_kh * 16 + q * 4);
        }
    };
    auto storec = [&](int ch, float* xbb, float* wbb) {
        if (half == 0 && L0 && ch < 4) {
            const int k0 = s_kg * 4, k1 = k0 + 16;
            xbb[(k0+0)*32 + s_bl] = rx0.x; xbb[(k0+1)*32 + s_bl] = rx0.y;
            xbb[(k0+2)*32 + s_bl] = rx0.z; xbb[(k0+3)*32 + s_bl] = rx0.w;
            xbb[(k1+0)*32 + s_bl] = rx1.x; xbb[(k1+1)*32 + s_bl] = rx1.y;
            xbb[(k1+2)*32 + s_bl] = rx1.z; xbb[(k1+3)*32 + s_bl] = rx1.w;
        } else {
            *(float4*)(xbb + s_kl * 32 + s_b4) = rx0;
            *(float4*)(xbb + (s_kl + 16) * 32 + s_b4) = rx1;
        }
#pragma unroll
        for (int q = 0; q < 4; ++q) {
            int kl = s_kh * 16 + q * 4;
            wbb[(kl+0)*64 + s_cl] = rw[q].x;
            wbb[(kl+1)*64 + s_cl] = rw[q].y;
            wbb[(kl+2)*64 + s_cl] = rw[q].z;
            wbb[(kl+3)*64 + s_cl] = rw[q].w;
        }
    };

    __syncthreads();                 // prior LDS users (epilogue/redS) done
    loadc(0);
    storec(0, xb, wb);
    for (int ch = 0; ch < NCH; ++ch) {
        __syncthreads();             // buf[ch&1] visible to all
        if (ch + 1 < NCH) loadc(ch + 1);       // global loads fly during fma
        const float* xp = xb + (ch & 1) * 1024 + bthr * 4;
        const float* wp = wb + (ch & 1) * 2048 + jthr * 4;
#pragma unroll 8
        for (int k = 0; k < 32; ++k) {
            float4 xv = *(const float4*)(xp + k * 32);   // 16-lane broadcast
            float4 wv = *(const float4*)(wp + k * 64);   // 4-way dup
            acc[0][0] = fmaf(xv.x, wv.x, acc[0][0]);
            acc[0][1] = fmaf(xv.x, wv.y, acc[0][1]);
            acc[0][2] = fmaf(xv.x, wv.z, acc[0][2]);
            acc[0][3] = fmaf(xv.x, wv.w, acc[0][3]);
            acc[1][0] = fmaf(xv.y, wv.x, acc[1][0]);
            acc[1][1] = fmaf(xv.y, wv.y, acc[1][1]);
            acc[1][2] = fmaf(xv.y, wv.z, acc[1][2]);
            acc[1][3] = fmaf(xv.y, wv.w, acc[1][3]);
            acc[2][0] = fmaf(xv.z, wv.x, acc[2][0]);
            acc[2][1] = fmaf(xv.z, wv.y, acc[2][1]);
            acc[2][2] = fmaf(xv.z, wv.z, acc[2][2]);
            acc[2][3] = fmaf(xv.z, wv.w, acc[2][3]);
            acc[3][0] = fmaf(xv.w, wv.x, acc[3][0]);
            acc[3][1] = fmaf(xv.w, wv.y, acc[3][1]);
            acc[3][2] = fmaf(xv.w, wv.z, acc[3][2]);
            acc[3][3] = fmaf(xv.w, wv.w, acc[3][3]);
        }
        if (ch + 1 < NCH)
            storec(ch + 1, xb + ((ch + 1) & 1) * 1024, wb + ((ch + 1) & 1) * 2048);
    }
    __syncthreads();                 // all fma done; buffers free for redS

    if (half == 1) {
#pragma unroll
        for (int bb = 0; bb < 4; ++bb)
            *(float4*)(redS + tid2 * 16 + bb * 4) =
                make_float4(acc[bb][0], acc[bb][1], acc[bb][2], acc[bb][3]);
    }
    __syncthreads();
    if (half == 0) {
        const int j   = jt * 16 + jthr;
        const int bb0 = b0g + bthr * 4;
        const float bi = bias[0*H + j], bf = bias[1*H + j];
        const float bg = bias[2*H + j], bo = bias[3*H + j];
        float4 cp = *(const float4*)(cst + (size_t)j * B + bb0);
        float cpa[4] = {cp.x, cp.y, cp.z, cp.w};
        float cn[4], hn[4];
#pragma unroll
        for (int bb = 0; bb < 4; ++bb) {
            float4 o = *(const float4*)(redS + tid2 * 16 + bb * 4);
            float gi = fsig (acc[bb][0] + o.x + bi);
            float gf = fsig (acc[bb][1] + o.y + bf);
            float gg = ftanh(acc[bb][2] + o.z + bg);
            float go = fsig (acc[bb][3] + o.w + bo);
            cn[bb] = gf * cpa[bb] + gi * gg;
            hn[bb] = go * ftanh(cn[bb]);
        }
        *(float4*)(cst  + (size_t)j * B + bb0) = make_float4(cn[0],cn[1],cn[2],cn[3]);
        *(float4*)(hout + (size_t)j * B + bb0) = make_float4(hn[0],hn[1],hn[2],hn[3]);
        if (!L0) {
#pragma unroll
            for (int bb = 0; bb < 4; ++bb) {
                int b = bb0 + bb;
                if (t <= last[b]) {                     // t == tt here
                    float m = hmaxp[(size_t)j * B + b];
                    hmaxp[(size_t)j * B + b] = fmaxf(m, hn[bb]);
                }
            }
        }
    }
}

// ---------------- persistent fused LSTM kernel ----------------
// 256 blocks x 256 threads, all co-resident. bid = bt*32 + jt -> XCD = jt%8:
// each j-tile's weight slice (~1.65 MB/XCD both layers) stays in its XCD L2
// across all steps. One device-scope barrier per fused step.
__global__ __launch_bounds__(256) void k_persist(
    const int* __restrict__ X, const float* __restrict__ embp,
    const float* __restrict__ Wih0, const float* __restrict__ Whh0,
    const float* __restrict__ b0,
    const float* __restrict__ Wih1, const float* __restrict__ Whh1,
    const float* __restrict__ b1,
    float* __restrict__ ws, unsigned* __restrict__ cnt)
{
    __shared__ float smem[12288];   // 48 KB: per half 24 KB (xb 2x4KB, wb 2x8KB)

    const int tid  = threadIdx.x;
    const int half = tid >> 7;
    const int tid2 = tid & 127;
    const int jt   = blockIdx.x & 31;
    const int bt   = blockIdx.x >> 5;
    const int b0g  = bt * 32;
    const int s_cl = tid2 & 63;
    const int wrow = (s_cl & 3) * H + jt * 16 + (s_cl >> 2);

    float* h0    = ws;
    float* c0    = ws + 2 * HB;
    float* h1    = ws + 3 * HB;
    float* c1    = ws + 5 * HB;
    float* hmaxp = ws + 6 * HB;
    const int* last = (const int*)(ws + 7 * HB);

    float* xb   = smem + half * 6144;
    float* wb   = smem + half * 6144 + 2048;
    float* redS = smem;                        // overlays half-0 xb (safe: sync'd)

    unsigned target = NBLK;
    for (int t = 0; t <= T; ++t) {
        if (t < T) {
            const float* hprev = h0 + ((t + 1) & 1) * HB;
            run_phase<true>(t, X, embp, hprev, hprev, Wih0, Whh0, b0,
                            c0, h0 + (t & 1) * HB, nullptr, last,
                            half, tid2, b0g, jt, wrow, xb, wb, redS);
        }
        if (t >= 1) {
            const int tt = t - 1;
            run_phase<false>(tt, X, embp,
                             h0 + (tt & 1) * HB,          // x = h0[tt]
                             h1 + ((tt + 1) & 1) * HB,    // h1[tt-1]
                             Wih1, Whh1, b1,
                             c1, h1 + (tt & 1) * HB, hmaxp, last,
                             half, tid2, b0g, jt, wrow, xb, wb, redS);
        }
        // ---- grid barrier (all blocks, every t) ----
        __threadfence();
        __syncthreads();
        if (tid == 0) {
            __hip_atomic_fetch_add(cnt, 1u, __ATOMIC_RELEASE, __HIP_MEMORY_SCOPE_AGENT);
            while (__hip_atomic_load(cnt, __ATOMIC_RELAXED, __HIP_MEMORY_SCOPE_AGENT) < target)
                __builtin_amdgcn_s_sleep(2);
        }
        __syncthreads();
        __threadfence();
        target += NBLK;
    }
}

// ---------------- final: logits[b][cls] = sum_j hmax[j][b] * Wout[cls][j] + bout ----
__global__ __launch_bounds__(64) void k_out(const float* __restrict__ hmax,
                                            const float* __restrict__ Wout,
                                            const float* __restrict__ bout,
                                            float* __restrict__ out) {
    const int b = blockIdx.x * 64 + threadIdx.x;
    float a[NC] = {0.f, 0.f, 0.f, 0.f, 0.f};
    const float* hm = hmax + b;
    for (int j = 0; j < H; ++j) {
        float hv = hm[j * B];
#pragma unroll
        for (int cls = 0; cls < NC; ++cls)
            a[cls] = fmaf(hv, Wout[cls * H + j], a[cls]);
    }
#pragma unroll
    for (int cls = 0; cls < NC; ++cls)
        out[b * NC + cls] = a[cls] + bout[cls];
}

// ---------------- launch ----------------
extern "C" void kernel_launch(void* const* d_in, const int* in_sizes, int n_in,
                              void* d_out, int out_size, void* d_ws, size_t ws_size,
                              hipStream_t stream) {
    const int*   X    = (const int*)  d_in[0];
    const float* emb  = (const float*)d_in[1];
    const float* Wih0 = (const float*)d_in[2];
    const float* Whh0 = (const float*)d_in[3];
    const float* b0   = (const float*)d_in[4];
    const float* Wih1 = (const float*)d_in[5];
    const float* Whh1 = (const float*)d_in[6];
    const float* b1   = (const float*)d_in[7];
    const float* Wout = (const float*)d_in[8];
    const float* bout = (const float*)d_in[9];
    float* out = (float*)d_out;
    float* ws  = (float*)d_ws;

    float*    hmax = ws + 6 * HB;
    int*      last = (int*)(ws + 7 * HB);
    unsigned* cnt  = (unsigned*)(ws + 7 * HB + B);

    k_init<<<(7 * HB + 255) / 256, 256, 0, stream>>>(ws, X, last, cnt);
    k_persist<<<NBLK, 256, 0, stream>>>(X, emb, Wih0, Whh0, b0,
                                        Wih1, Whh1, b1, ws, cnt);
    k_out<<<4, 64, 0, stream>>>(hmax, Wout, bout, out);
}